// Round 5
// baseline (502.813 us; speedup 1.0000x reference)
//
#include <hip/hip_runtime.h>
#include <math.h>

typedef float v4 __attribute__((ext_vector_type(4)));
typedef float f32x4 __attribute__((ext_vector_type(4)));
typedef __bf16 bf16x8 __attribute__((ext_vector_type(8)));

#define HD 1024      // hidden dim
#define NB 64        // batch

// ws layout (float offsets)
#define WS_IGT  0         // igT [1024][64]   exp(i-gate), transposed
#define WS_FGT  65536     // fgT [1024][64]   exp(f-gate)
#define WS_QT   131072    // qT  [1024][64]
#define WS_VT   196608    // vT  [1024][64]
#define WS_OGN  262144    // ogN [64][1024]   sigmoid(o), natural
#define WS_KN   327680    // kN  [64][1024]   natural
#define WS_BPK  393216    // bf16 x/h B-fragments [64 ks][4 bt][64 lane][8] = 65536 floats
#define WS_PART 458752    // readout partials [32 c][64 b][1024] = 2,097,152 floats
// total = 2,555,904 floats = 10.2 MB

// ---------------- kernel 1: pack x/h to bf16 MFMA B-fragments (tiny) ------------
__global__ __launch_bounds__(256) void k_prepb(const float* __restrict__ input,
                                               const float* __restrict__ h,
                                               float* __restrict__ ws) {
    int o = blockIdx.x * 256 + threadIdx.x;     // 0..16383
    int l  = o & 63;
    int bt = (o >> 6) & 3;
    int ks = o >> 8;                            // 0..63
    const float* srcm = (ks < 32) ? input : h;
    const float* src = srcm + (size_t)(bt * 16 + (l & 15)) * HD + (ks & 31) * 32 + (l >> 4) * 8;
    v4 f0 = *(const v4*)src;
    v4 f1 = *(const v4*)(src + 4);
    bf16x8 pk;
    pk[0] = (__bf16)f0.x; pk[1] = (__bf16)f0.y; pk[2] = (__bf16)f0.z; pk[3] = (__bf16)f0.w;
    pk[4] = (__bf16)f1.x; pk[5] = (__bf16)f1.y; pk[6] = (__bf16)f1.z; pk[7] = (__bf16)f1.w;
    *((bf16x8*)((__bf16*)(ws + WS_BPK)) + o) = pk;
}

// ---------------- kernel 2: fused MFMA GEMM + bias + activations (round-3 body) --
__global__ __launch_bounds__(256) void k_gemm(
    const float* __restrict__ Wih, const float* __restrict__ Whh, const float* __restrict__ bias,
    const float* __restrict__ Wq, const float* __restrict__ Wqb,
    const float* __restrict__ Wk, const float* __restrict__ Wkb,
    const float* __restrict__ Wv, const float* __restrict__ Wvb,
    float* __restrict__ ws) {
    int tid  = threadIdx.x;
    int lane = tid & 63;
    int w    = tid >> 6;          // 0..3
    int t    = blockIdx.x;

    const bf16x8* Bp = (const bf16x8*)((const __bf16*)(ws + WS_BPK));
    __shared__ f32x4 red[4][4][64];   // [wave][b-tile][lane]

    f32x4 a0 = {0.f, 0.f, 0.f, 0.f};
    f32x4 a1 = a0, a2 = a0, a3 = a0;

    if (t < 192) {
        int row = t * 16 + (lane & 15);
        const float* Wb = (w < 2) ? Wih : Whh;
        const float* wrow = Wb + (size_t)row * HD + (lane >> 4) * 8;
        int cofs = (w < 2) ? 0 : -1024;
        int s0 = w * 16;
        #pragma unroll 4
        for (int s = 0; s < 16; ++s) {
            int ks = s0 + s;
            const float* ap = wrow + ks * 32 + cofs;
            v4 f0 = *(const v4*)ap;
            v4 f1 = *(const v4*)(ap + 4);
            bf16x8 a;
            a[0] = (__bf16)f0.x; a[1] = (__bf16)f0.y; a[2] = (__bf16)f0.z; a[3] = (__bf16)f0.w;
            a[4] = (__bf16)f1.x; a[5] = (__bf16)f1.y; a[6] = (__bf16)f1.z; a[7] = (__bf16)f1.w;
            const bf16x8* bb = Bp + (size_t)ks * 256 + lane;
            bf16x8 b0 = bb[0], b1 = bb[64], b2 = bb[128], b3 = bb[192];
            a0 = __builtin_amdgcn_mfma_f32_16x16x32_bf16(a, b0, a0, 0, 0, 0);
            a1 = __builtin_amdgcn_mfma_f32_16x16x32_bf16(a, b1, a1, 0, 0, 0);
            a2 = __builtin_amdgcn_mfma_f32_16x16x32_bf16(a, b2, a2, 0, 0, 0);
            a3 = __builtin_amdgcn_mfma_f32_16x16x32_bf16(a, b3, a3, 0, 0, 0);
        }
    } else {
        int t2  = t - 192;
        int sel = t2 >> 6;
        const float* W = (sel == 0) ? Wq : (sel == 1) ? Wk : Wv;
        int row = (t2 & 63) * 16 + (lane & 15);
        const float* wrow = W + (size_t)row * HD + (lane >> 4) * 8;
        int s0 = w * 8;
        #pragma unroll 4
        for (int s = 0; s < 8; ++s) {
            int ks = s0 + s;
            const float* ap = wrow + ks * 32;
            v4 f0 = *(const v4*)ap;
            v4 f1 = *(const v4*)(ap + 4);
            bf16x8 a;
            a[0] = (__bf16)f0.x; a[1] = (__bf16)f0.y; a[2] = (__bf16)f0.z; a[3] = (__bf16)f0.w;
            a[4] = (__bf16)f1.x; a[5] = (__bf16)f1.y; a[6] = (__bf16)f1.z; a[7] = (__bf16)f1.w;
            const bf16x8* bb = Bp + (size_t)ks * 256 + lane;
            bf16x8 b0 = bb[0], b1 = bb[64], b2 = bb[128], b3 = bb[192];
            a0 = __builtin_amdgcn_mfma_f32_16x16x32_bf16(a, b0, a0, 0, 0, 0);
            a1 = __builtin_amdgcn_mfma_f32_16x16x32_bf16(a, b1, a1, 0, 0, 0);
            a2 = __builtin_amdgcn_mfma_f32_16x16x32_bf16(a, b2, a2, 0, 0, 0);
            a3 = __builtin_amdgcn_mfma_f32_16x16x32_bf16(a, b3, a3, 0, 0, 0);
        }
    }

    red[w][0][lane] = a0;
    red[w][1][lane] = a1;
    red[w][2][lane] = a2;
    red[w][3][lane] = a3;
    __syncthreads();

    int b    = tid & 63;
    int rgrp = tid >> 6;
    int lane2 = (rgrp << 4) | (b & 15);
    int bt    = b >> 4;
    f32x4 s4 = red[0][bt][lane2];
    s4 += red[1][bt][lane2];
    s4 += red[2][bt][lane2];
    s4 += red[3][bt][lane2];

    if (t < 192) {
        int seg  = t >> 6;
        int rloc = (t & 63) * 16 + rgrp * 4;
        int rg   = t * 16 + rgrp * 4;
        if (seg == 0) {
            #pragma unroll
            for (int q = 0; q < 4; ++q)
                ws[WS_IGT + (rloc + q) * 64 + b] = expf(s4[q] + bias[rg + q]);
        } else if (seg == 1) {
            #pragma unroll
            for (int q = 0; q < 4; ++q)
                ws[WS_FGT + (rloc + q) * 64 + b] = expf(s4[q] + bias[rg + q]);
        } else {
            v4 o;
            #pragma unroll
            for (int q = 0; q < 4; ++q) {
                float x = s4[q] + bias[rg + q];
                o[q] = 1.f / (1.f + expf(-x));
            }
            *(v4*)(ws + WS_OGN + b * HD + rloc) = o;
        }
    } else {
        int t2   = t - 192;
        int sel  = t2 >> 6;
        int rloc = (t2 & 63) * 16 + rgrp * 4;
        const float* Bv = (sel == 0) ? Wqb : (sel == 1) ? Wkb : Wvb;
        if (sel == 0) {
            #pragma unroll
            for (int q = 0; q < 4; ++q)
                ws[WS_QT + (rloc + q) * 64 + b] = s4[q] + Bv[rloc + q];
        } else if (sel == 1) {
            v4 kv;
            #pragma unroll
            for (int q = 0; q < 4; ++q) kv[q] = s4[q] + Bv[rloc + q];
            *(v4*)(ws + WS_KN + b * HD + rloc) = kv;
        } else {
            #pragma unroll
            for (int q = 0; q < 4; ++q)
                ws[WS_VT + (rloc + q) * 64 + b] = s4[q] + Bv[rloc + q];
        }
    }
}

// ---------------- kernel 3: C update + fused readout partials -------------------
// Rewritten: NO nontemporal hints, NO full unroll (VGPR kept low for 32 waves/CU),
// explicit software pipeline: prefetch next 4 rows before computing current 4,
// compute in-place so stores reuse the load registers.
__global__ __launch_bounds__(256) void k_update(const float* __restrict__ C,
                                                float* __restrict__ out,
                                                float* __restrict__ ws) {
    int b  = blockIdx.x >> 5;
    int c  = blockIdx.x & 31;
    int i0 = c << 5;
    int tid = threadIdx.x;

    __shared__ float fg_s[32], iv_s[32], q_s[32];
    if (tid < 32) {
        int i = i0 + tid;
        fg_s[tid] = ws[WS_FGT + i * 64 + b];
        iv_s[tid] = ws[WS_IGT + i * 64 + b] * ws[WS_VT + i * 64 + b];
        q_s[tid]  = ws[WS_QT + i * 64 + b];
    }
    __syncthreads();

    v4 k4 = *(const v4*)(ws + WS_KN + b * HD + tid * 4);
    const v4* Cb = (const v4*)(C + (size_t)b * HD * HD) + (size_t)i0 * 256 + tid;
    v4*       On = (v4*)(out + NB * HD + (size_t)b * HD * HD) + (size_t)i0 * 256 + tid;
    v4 acc0 = {0.f, 0.f, 0.f, 0.f};
    v4 acc1 = {0.f, 0.f, 0.f, 0.f};

    v4 c0 = Cb[0], c1 = Cb[256], c2 = Cb[512], c3 = Cb[768];
    #pragma unroll 1
    for (int ii = 0; ii < 32; ii += 4) {
        v4 p0, p1, p2, p3;
        if (ii < 28) {
            size_t rn = (size_t)(ii + 4) * 256;
            p0 = Cb[rn]; p1 = Cb[rn + 256]; p2 = Cb[rn + 512]; p3 = Cb[rn + 768];
        }
        v4 fv = *(const v4*)&fg_s[ii];
        v4 gv = *(const v4*)&iv_s[ii];
        v4 qv = *(const v4*)&q_s[ii];

        c0.x = fv.x * c0.x + gv.x * k4.x; c0.y = fv.x * c0.y + gv.x * k4.y;
        c0.z = fv.x * c0.z + gv.x * k4.z; c0.w = fv.x * c0.w + gv.x * k4.w;
        c1.x = fv.y * c1.x + gv.y * k4.x; c1.y = fv.y * c1.y + gv.y * k4.y;
        c1.z = fv.y * c1.z + gv.y * k4.z; c1.w = fv.y * c1.w + gv.y * k4.w;
        c2.x = fv.z * c2.x + gv.z * k4.x; c2.y = fv.z * c2.y + gv.z * k4.y;
        c2.z = fv.z * c2.z + gv.z * k4.z; c2.w = fv.z * c2.w + gv.z * k4.w;
        c3.x = fv.w * c3.x + gv.w * k4.x; c3.y = fv.w * c3.y + gv.w * k4.y;
        c3.z = fv.w * c3.z + gv.w * k4.z; c3.w = fv.w * c3.w + gv.w * k4.w;

        size_t r0 = (size_t)ii * 256;
        On[r0]       = c0;
        On[r0 + 256] = c1;
        On[r0 + 512] = c2;
        On[r0 + 768] = c3;

        acc0.x += qv.x * c0.x; acc0.y += qv.x * c0.y; acc0.z += qv.x * c0.z; acc0.w += qv.x * c0.w;
        acc1.x += qv.y * c1.x; acc1.y += qv.y * c1.y; acc1.z += qv.y * c1.z; acc1.w += qv.y * c1.w;
        acc0.x += qv.z * c2.x; acc0.y += qv.z * c2.y; acc0.z += qv.z * c2.z; acc0.w += qv.z * c2.w;
        acc1.x += qv.w * c3.x; acc1.y += qv.w * c3.y; acc1.z += qv.w * c3.z; acc1.w += qv.w * c3.w;

        c0 = p0; c1 = p1; c2 = p2; c3 = p3;
    }
    v4 acc;
    acc.x = acc0.x + acc1.x; acc.y = acc0.y + acc1.y;
    acc.z = acc0.z + acc1.z; acc.w = acc0.w + acc1.w;
    *(v4*)(ws + WS_PART + (size_t)(c * 64 + b) * HD + tid * 4) = acc;
}

// ---------------- kernel 4: finalize h ------------------------------------------
__global__ __launch_bounds__(256) void k_final(float* __restrict__ out,
                                               const float* __restrict__ ws) {
    int b = blockIdx.x;
    int tid = threadIdx.x;
    const v4* part = (const v4*)(ws + WS_PART);
    v4 s = {0.f, 0.f, 0.f, 0.f};
    #pragma unroll 4
    for (int c = 0; c < 32; ++c) {
        v4 p = part[(size_t)(c * 64 + b) * 256 + tid];
        s.x += p.x; s.y += p.y; s.z += p.z; s.w += p.w;
    }
    v4 o4 = *(const v4*)(ws + WS_OGN + b * HD + tid * 4);
    v4 r;
    r.x = o4.x * s.x; r.y = o4.y * s.y; r.z = o4.z * s.z; r.w = o4.w * s.w;
    *(v4*)(out + b * HD + tid * 4) = r;
}

extern "C" void kernel_launch(void* const* d_in, const int* in_sizes, int n_in,
                              void* d_out, int out_size, void* d_ws, size_t ws_size,
                              hipStream_t stream) {
    const float* input = (const float*)d_in[0];
    const float* h     = (const float*)d_in[1];
    const float* C     = (const float*)d_in[2];
    const float* Wih   = (const float*)d_in[3];
    const float* Whh   = (const float*)d_in[4];
    const float* bias  = (const float*)d_in[5];
    const float* Wq_w  = (const float*)d_in[6];
    const float* Wq_b  = (const float*)d_in[7];
    const float* Wk_w  = (const float*)d_in[8];
    const float* Wk_b  = (const float*)d_in[9];
    const float* Wv_w  = (const float*)d_in[10];
    const float* Wv_b  = (const float*)d_in[11];
    float* out = (float*)d_out;
    float* ws  = (float*)d_ws;

    k_prepb<<<64, 256, 0, stream>>>(input, h, ws);
    k_gemm<<<384, 256, 0, stream>>>(Wih, Whh, bias, Wq_w, Wq_b, Wk_w, Wk_b, Wv_w, Wv_b, ws);
    k_update<<<2048, 256, 0, stream>>>(C, out, ws);
    k_final<<<64, 256, 0, stream>>>(out, ws);
}

// Round 6
// 483.838 us; speedup vs baseline: 1.0392x; 1.0392x over previous
//
#include <hip/hip_runtime.h>
#include <math.h>

typedef float v4 __attribute__((ext_vector_type(4)));
typedef float f32x4 __attribute__((ext_vector_type(4)));
typedef __bf16 bf16x8 __attribute__((ext_vector_type(8)));

#define HD 1024      // hidden dim
#define NB 64        // batch

// ws layout (float offsets)
#define WS_IGT  0         // igT [1024][64]   exp(i-gate), transposed
#define WS_FGT  65536     // fgT [1024][64]   exp(f-gate)
#define WS_QT   131072    // qT  [1024][64]
#define WS_VT   196608    // vT  [1024][64]
#define WS_OGN  262144    // ogN [64][1024]   sigmoid(o), natural
#define WS_KN   327680    // kN  [64][1024]   natural
#define WS_BPK  393216    // bf16 x/h B-fragments [64 ks][4 bt][64 lane][8] = 65536 floats
#define WS_PART 458752    // readout partials [32 c][64 b][1024] = 2,097,152 floats
// total = 2,555,904 floats = 10.2 MB

// ---------------- kernel 1: pack x/h to bf16 MFMA B-fragments (tiny) ------------
__global__ __launch_bounds__(256) void k_prepb(const float* __restrict__ input,
                                               const float* __restrict__ h,
                                               float* __restrict__ ws) {
    int o = blockIdx.x * 256 + threadIdx.x;     // 0..16383
    int l  = o & 63;
    int bt = (o >> 6) & 3;
    int ks = o >> 8;                            // 0..63
    const float* srcm = (ks < 32) ? input : h;
    const float* src = srcm + (size_t)(bt * 16 + (l & 15)) * HD + (ks & 31) * 32 + (l >> 4) * 8;
    v4 f0 = *(const v4*)src;
    v4 f1 = *(const v4*)(src + 4);
    bf16x8 pk;
    pk[0] = (__bf16)f0.x; pk[1] = (__bf16)f0.y; pk[2] = (__bf16)f0.z; pk[3] = (__bf16)f0.w;
    pk[4] = (__bf16)f1.x; pk[5] = (__bf16)f1.y; pk[6] = (__bf16)f1.z; pk[7] = (__bf16)f1.w;
    *((bf16x8*)((__bf16*)(ws + WS_BPK)) + o) = pk;
}

// ---------------- kernel 2: fused MFMA GEMM + bias + activations (round-3 body) --
__global__ __launch_bounds__(256) void k_gemm(
    const float* __restrict__ Wih, const float* __restrict__ Whh, const float* __restrict__ bias,
    const float* __restrict__ Wq, const float* __restrict__ Wqb,
    const float* __restrict__ Wk, const float* __restrict__ Wkb,
    const float* __restrict__ Wv, const float* __restrict__ Wvb,
    float* __restrict__ ws) {
    int tid  = threadIdx.x;
    int lane = tid & 63;
    int w    = tid >> 6;          // 0..3
    int t    = blockIdx.x;

    const bf16x8* Bp = (const bf16x8*)((const __bf16*)(ws + WS_BPK));
    __shared__ f32x4 red[4][4][64];   // [wave][b-tile][lane]

    f32x4 a0 = {0.f, 0.f, 0.f, 0.f};
    f32x4 a1 = a0, a2 = a0, a3 = a0;

    if (t < 192) {
        int row = t * 16 + (lane & 15);
        const float* Wb = (w < 2) ? Wih : Whh;
        const float* wrow = Wb + (size_t)row * HD + (lane >> 4) * 8;
        int cofs = (w < 2) ? 0 : -1024;
        int s0 = w * 16;
        #pragma unroll 4
        for (int s = 0; s < 16; ++s) {
            int ks = s0 + s;
            const float* ap = wrow + ks * 32 + cofs;
            v4 f0 = *(const v4*)ap;
            v4 f1 = *(const v4*)(ap + 4);
            bf16x8 a;
            a[0] = (__bf16)f0.x; a[1] = (__bf16)f0.y; a[2] = (__bf16)f0.z; a[3] = (__bf16)f0.w;
            a[4] = (__bf16)f1.x; a[5] = (__bf16)f1.y; a[6] = (__bf16)f1.z; a[7] = (__bf16)f1.w;
            const bf16x8* bb = Bp + (size_t)ks * 256 + lane;
            bf16x8 b0 = bb[0], b1 = bb[64], b2 = bb[128], b3 = bb[192];
            a0 = __builtin_amdgcn_mfma_f32_16x16x32_bf16(a, b0, a0, 0, 0, 0);
            a1 = __builtin_amdgcn_mfma_f32_16x16x32_bf16(a, b1, a1, 0, 0, 0);
            a2 = __builtin_amdgcn_mfma_f32_16x16x32_bf16(a, b2, a2, 0, 0, 0);
            a3 = __builtin_amdgcn_mfma_f32_16x16x32_bf16(a, b3, a3, 0, 0, 0);
        }
    } else {
        int t2  = t - 192;
        int sel = t2 >> 6;
        const float* W = (sel == 0) ? Wq : (sel == 1) ? Wk : Wv;
        int row = (t2 & 63) * 16 + (lane & 15);
        const float* wrow = W + (size_t)row * HD + (lane >> 4) * 8;
        int s0 = w * 8;
        #pragma unroll 4
        for (int s = 0; s < 8; ++s) {
            int ks = s0 + s;
            const float* ap = wrow + ks * 32;
            v4 f0 = *(const v4*)ap;
            v4 f1 = *(const v4*)(ap + 4);
            bf16x8 a;
            a[0] = (__bf16)f0.x; a[1] = (__bf16)f0.y; a[2] = (__bf16)f0.z; a[3] = (__bf16)f0.w;
            a[4] = (__bf16)f1.x; a[5] = (__bf16)f1.y; a[6] = (__bf16)f1.z; a[7] = (__bf16)f1.w;
            const bf16x8* bb = Bp + (size_t)ks * 256 + lane;
            bf16x8 b0 = bb[0], b1 = bb[64], b2 = bb[128], b3 = bb[192];
            a0 = __builtin_amdgcn_mfma_f32_16x16x32_bf16(a, b0, a0, 0, 0, 0);
            a1 = __builtin_amdgcn_mfma_f32_16x16x32_bf16(a, b1, a1, 0, 0, 0);
            a2 = __builtin_amdgcn_mfma_f32_16x16x32_bf16(a, b2, a2, 0, 0, 0);
            a3 = __builtin_amdgcn_mfma_f32_16x16x32_bf16(a, b3, a3, 0, 0, 0);
        }
    }

    red[w][0][lane] = a0;
    red[w][1][lane] = a1;
    red[w][2][lane] = a2;
    red[w][3][lane] = a3;
    __syncthreads();

    int b    = tid & 63;
    int rgrp = tid >> 6;
    int lane2 = (rgrp << 4) | (b & 15);
    int bt    = b >> 4;
    f32x4 s4 = red[0][bt][lane2];
    s4 += red[1][bt][lane2];
    s4 += red[2][bt][lane2];
    s4 += red[3][bt][lane2];

    if (t < 192) {
        int seg  = t >> 6;
        int rloc = (t & 63) * 16 + rgrp * 4;
        int rg   = t * 16 + rgrp * 4;
        if (seg == 0) {
            #pragma unroll
            for (int q = 0; q < 4; ++q)
                ws[WS_IGT + (rloc + q) * 64 + b] = expf(s4[q] + bias[rg + q]);
        } else if (seg == 1) {
            #pragma unroll
            for (int q = 0; q < 4; ++q)
                ws[WS_FGT + (rloc + q) * 64 + b] = expf(s4[q] + bias[rg + q]);
        } else {
            v4 o;
            #pragma unroll
            for (int q = 0; q < 4; ++q) {
                float x = s4[q] + bias[rg + q];
                o[q] = 1.f / (1.f + expf(-x));
            }
            *(v4*)(ws + WS_OGN + b * HD + rloc) = o;
        }
    } else {
        int t2   = t - 192;
        int sel  = t2 >> 6;
        int rloc = (t2 & 63) * 16 + rgrp * 4;
        const float* Bv = (sel == 0) ? Wqb : (sel == 1) ? Wkb : Wvb;
        if (sel == 0) {
            #pragma unroll
            for (int q = 0; q < 4; ++q)
                ws[WS_QT + (rloc + q) * 64 + b] = s4[q] + Bv[rloc + q];
        } else if (sel == 1) {
            v4 kv;
            #pragma unroll
            for (int q = 0; q < 4; ++q) kv[q] = s4[q] + Bv[rloc + q];
            *(v4*)(ws + WS_KN + b * HD + rloc) = kv;
        } else {
            #pragma unroll
            for (int q = 0; q < 4; ++q)
                ws[WS_VT + (rloc + q) * 64 + b] = s4[q] + Bv[rloc + q];
        }
    }
}

// ---------------- kernel 3: C update + fused readout partials -------------------
// NT hints RESTORED (round-5 showed they're worth ~20 µs); distance-2 register
// double-buffer with #pragma unroll 1 so load-use waits aren't entangled with
// store bursts; VGPR kept low (two 4-row batches live) for 8 waves/SIMD.
__global__ __launch_bounds__(256) void k_update(const float* __restrict__ C,
                                                float* __restrict__ out,
                                                float* __restrict__ ws) {
    int b  = blockIdx.x >> 5;
    int c  = blockIdx.x & 31;
    int i0 = c << 5;
    int tid = threadIdx.x;

    __shared__ float fg_s[32], iv_s[32], q_s[32];
    if (tid < 32) {
        int i = i0 + tid;
        fg_s[tid] = ws[WS_FGT + i * 64 + b];
        iv_s[tid] = ws[WS_IGT + i * 64 + b] * ws[WS_VT + i * 64 + b];
        q_s[tid]  = ws[WS_QT + i * 64 + b];
    }
    __syncthreads();

    v4 k4 = *(const v4*)(ws + WS_KN + b * HD + tid * 4);
    const v4* Cb = (const v4*)(C + (size_t)b * HD * HD) + (size_t)i0 * 256 + tid;
    v4*       On = (v4*)(out + NB * HD + (size_t)b * HD * HD) + (size_t)i0 * 256 + tid;
    v4 acc0 = {0.f, 0.f, 0.f, 0.f};
    v4 acc1 = {0.f, 0.f, 0.f, 0.f};

    // prologue: batches 0 (rows 0-3) and 1 (rows 4-7) in flight
    v4 x0 = __builtin_nontemporal_load(&Cb[0]);
    v4 x1 = __builtin_nontemporal_load(&Cb[256]);
    v4 x2 = __builtin_nontemporal_load(&Cb[512]);
    v4 x3 = __builtin_nontemporal_load(&Cb[768]);
    v4 y0 = __builtin_nontemporal_load(&Cb[1024]);
    v4 y1 = __builtin_nontemporal_load(&Cb[1280]);
    v4 y2 = __builtin_nontemporal_load(&Cb[1536]);
    v4 y3 = __builtin_nontemporal_load(&Cb[1792]);

    #pragma unroll 1
    for (int ii = 0; ii < 32; ii += 8) {
        // ---- batch X: rows ii .. ii+3 ----
        {
            v4 fv = *(const v4*)&fg_s[ii];
            v4 gv = *(const v4*)&iv_s[ii];
            v4 qv = *(const v4*)&q_s[ii];
            x0.x = fv.x * x0.x + gv.x * k4.x; x0.y = fv.x * x0.y + gv.x * k4.y;
            x0.z = fv.x * x0.z + gv.x * k4.z; x0.w = fv.x * x0.w + gv.x * k4.w;
            x1.x = fv.y * x1.x + gv.y * k4.x; x1.y = fv.y * x1.y + gv.y * k4.y;
            x1.z = fv.y * x1.z + gv.y * k4.z; x1.w = fv.y * x1.w + gv.y * k4.w;
            x2.x = fv.z * x2.x + gv.z * k4.x; x2.y = fv.z * x2.y + gv.z * k4.y;
            x2.z = fv.z * x2.z + gv.z * k4.z; x2.w = fv.z * x2.w + gv.z * k4.w;
            x3.x = fv.w * x3.x + gv.w * k4.x; x3.y = fv.w * x3.y + gv.w * k4.y;
            x3.z = fv.w * x3.z + gv.w * k4.z; x3.w = fv.w * x3.w + gv.w * k4.w;

            acc0.x += qv.x * x0.x; acc0.y += qv.x * x0.y; acc0.z += qv.x * x0.z; acc0.w += qv.x * x0.w;
            acc1.x += qv.y * x1.x; acc1.y += qv.y * x1.y; acc1.z += qv.y * x1.z; acc1.w += qv.y * x1.w;
            acc0.x += qv.z * x2.x; acc0.y += qv.z * x2.y; acc0.z += qv.z * x2.z; acc0.w += qv.z * x2.w;
            acc1.x += qv.w * x3.x; acc1.y += qv.w * x3.y; acc1.z += qv.w * x3.z; acc1.w += qv.w * x3.w;

            size_t r0 = (size_t)ii * 256;
            __builtin_nontemporal_store(x0, &On[r0]);
            __builtin_nontemporal_store(x1, &On[r0 + 256]);
            __builtin_nontemporal_store(x2, &On[r0 + 512]);
            __builtin_nontemporal_store(x3, &On[r0 + 768]);
        }
        if (ii < 24) {        // prefetch batch ii+8 (distance 2)
            size_t rn = (size_t)(ii + 8) * 256;
            x0 = __builtin_nontemporal_load(&Cb[rn]);
            x1 = __builtin_nontemporal_load(&Cb[rn + 256]);
            x2 = __builtin_nontemporal_load(&Cb[rn + 512]);
            x3 = __builtin_nontemporal_load(&Cb[rn + 768]);
        }
        // ---- batch Y: rows ii+4 .. ii+7 ----
        {
            v4 fv = *(const v4*)&fg_s[ii + 4];
            v4 gv = *(const v4*)&iv_s[ii + 4];
            v4 qv = *(const v4*)&q_s[ii + 4];
            y0.x = fv.x * y0.x + gv.x * k4.x; y0.y = fv.x * y0.y + gv.x * k4.y;
            y0.z = fv.x * y0.z + gv.x * k4.z; y0.w = fv.x * y0.w + gv.x * k4.w;
            y1.x = fv.y * y1.x + gv.y * k4.x; y1.y = fv.y * y1.y + gv.y * k4.y;
            y1.z = fv.y * y1.z + gv.y * k4.z; y1.w = fv.y * y1.w + gv.y * k4.w;
            y2.x = fv.z * y2.x + gv.z * k4.x; y2.y = fv.z * y2.y + gv.z * k4.y;
            y2.z = fv.z * y2.z + gv.z * k4.z; y2.w = fv.z * y2.w + gv.z * k4.w;
            y3.x = fv.w * y3.x + gv.w * k4.x; y3.y = fv.w * y3.y + gv.w * k4.y;
            y3.z = fv.w * y3.z + gv.w * k4.z; y3.w = fv.w * y3.w + gv.w * k4.w;

            acc0.x += qv.x * y0.x; acc0.y += qv.x * y0.y; acc0.z += qv.x * y0.z; acc0.w += qv.x * y0.w;
            acc1.x += qv.y * y1.x; acc1.y += qv.y * y1.y; acc1.z += qv.y * y1.z; acc1.w += qv.y * y1.w;
            acc0.x += qv.z * y2.x; acc0.y += qv.z * y2.y; acc0.z += qv.z * y2.z; acc0.w += qv.z * y2.w;
            acc1.x += qv.w * y3.x; acc1.y += qv.w * y3.y; acc1.z += qv.w * y3.z; acc1.w += qv.w * y3.w;

            size_t r4 = (size_t)(ii + 4) * 256;
            __builtin_nontemporal_store(y0, &On[r4]);
            __builtin_nontemporal_store(y1, &On[r4 + 256]);
            __builtin_nontemporal_store(y2, &On[r4 + 512]);
            __builtin_nontemporal_store(y3, &On[r4 + 768]);
        }
        if (ii < 24) {        // prefetch batch ii+12 (distance 2)
            size_t rn = (size_t)(ii + 12) * 256;
            y0 = __builtin_nontemporal_load(&Cb[rn]);
            y1 = __builtin_nontemporal_load(&Cb[rn + 256]);
            y2 = __builtin_nontemporal_load(&Cb[rn + 512]);
            y3 = __builtin_nontemporal_load(&Cb[rn + 768]);
        }
    }
    v4 acc;
    acc.x = acc0.x + acc1.x; acc.y = acc0.y + acc1.y;
    acc.z = acc0.z + acc1.z; acc.w = acc0.w + acc1.w;
    *(v4*)(ws + WS_PART + (size_t)(c * 64 + b) * HD + tid * 4) = acc;
}

// ---------------- kernel 4: finalize h ------------------------------------------
__global__ __launch_bounds__(256) void k_final(float* __restrict__ out,
                                               const float* __restrict__ ws) {
    int b = blockIdx.x;
    int tid = threadIdx.x;
    const v4* part = (const v4*)(ws + WS_PART);
    v4 s = {0.f, 0.f, 0.f, 0.f};
    #pragma unroll 4
    for (int c = 0; c < 32; ++c) {
        v4 p = part[(size_t)(c * 64 + b) * 256 + tid];
        s.x += p.x; s.y += p.y; s.z += p.z; s.w += p.w;
    }
    v4 o4 = *(const v4*)(ws + WS_OGN + b * HD + tid * 4);
    v4 r;
    r.x = o4.x * s.x; r.y = o4.y * s.y; r.z = o4.z * s.z; r.w = o4.w * s.w;
    *(v4*)(out + b * HD + tid * 4) = r;
}

extern "C" void kernel_launch(void* const* d_in, const int* in_sizes, int n_in,
                              void* d_out, int out_size, void* d_ws, size_t ws_size,
                              hipStream_t stream) {
    const float* input = (const float*)d_in[0];
    const float* h     = (const float*)d_in[1];
    const float* C     = (const float*)d_in[2];
    const float* Wih   = (const float*)d_in[3];
    const float* Whh   = (const float*)d_in[4];
    const float* bias  = (const float*)d_in[5];
    const float* Wq_w  = (const float*)d_in[6];
    const float* Wq_b  = (const float*)d_in[7];
    const float* Wk_w  = (const float*)d_in[8];
    const float* Wk_b  = (const float*)d_in[9];
    const float* Wv_w  = (const float*)d_in[10];
    const float* Wv_b  = (const float*)d_in[11];
    float* out = (float*)d_out;
    float* ws  = (float*)d_ws;

    k_prepb<<<64, 256, 0, stream>>>(input, h, ws);
    k_gemm<<<384, 256, 0, stream>>>(Wih, Whh, bias, Wq_w, Wq_b, Wk_w, Wk_b, Wv_w, Wv_b, ws);
    k_update<<<2048, 256, 0, stream>>>(C, out, ws);
    k_final<<<64, 256, 0, stream>>>(out, ws);
}